// Round 1
// baseline (47.798 us; speedup 1.0000x reference)
//
#include <hip/hip_runtime.h>

#define B_N   2048
#define IM    16
#define LQ    10
#define KITER 20
#define LH    150

// ws layout (floats): [0..17] eff_w (c*9 + ky*3 + kx), [18] eff_b, [19..27] fw[t]
__global__ void vin_precompute(const float* __restrict__ h_w,
                               const float* __restrict__ h_b,
                               const float* __restrict__ r_w,
                               const float* __restrict__ w,
                               const float* __restrict__ fc_w,
                               float* __restrict__ ws) {
    int t = threadIdx.x;
    if (t < 18) {
        float acc = 0.f;
        for (int h = 0; h < LH; ++h) acc += r_w[h] * h_w[h * 18 + t];
        ws[t] = acc;
    } else if (t == 18) {
        float acc = 0.f;
        for (int h = 0; h < LH; ++h) acc += r_w[h] * h_b[h];
        ws[18] = acc;
    } else if (t < 28) {
        int tt = t - 19;
        float acc = 0.f;
        for (int a = 0; a < LQ; ++a) acc += fc_w[a] * w[a * 9 + tt];
        ws[19 + tt] = acc;
    }
}

__global__ __launch_bounds__(256) void vin_kernel(
    const float* __restrict__ X,  const float* __restrict__ S1,
    const float* __restrict__ S2, const float* __restrict__ qw,
    const float* __restrict__ w,  const float* __restrict__ fcw,
    const float* __restrict__ ws, float* __restrict__ out) {

    __shared__ float xs[2][18][18];   // padded X
    __shared__ float rp[18][18];      // padded r
    __shared__ float vp[2][18][18];   // double-buffered padded v

    const int b   = blockIdx.x;
    const int tid = threadIdx.x;
    const int i   = tid >> 4;
    const int j   = tid & 15;

    // zero all LDS once (borders must be 0 for implicit padding)
    {
        float* lds = &xs[0][0][0];
        #pragma unroll
        for (int k = 0; k < 7; ++k) {
            int idx = tid + k * 256;
            if (idx < 5 * 18 * 18) lds[idx] = 0.f;
        }
    }
    __syncthreads();

    // stage X[b] (coalesced: tid maps to i*16+j, contiguous in memory)
    xs[0][i + 1][j + 1] = X[(size_t)b * 512 + tid];
    xs[1][i + 1][j + 1] = X[(size_t)b * 512 + 256 + tid];
    __syncthreads();

    // r = conv3x3(X, eff_w) + eff_b   (collapsed 150-channel hidden layer)
    float racc = ws[18];
    #pragma unroll
    for (int c = 0; c < 2; ++c)
        #pragma unroll
        for (int ky = 0; ky < 3; ++ky)
            #pragma unroll
            for (int kx = 0; kx < 3; ++kx)
                racc += xs[c][i + ky][j + kx] * ws[c * 9 + ky * 3 + kx];
    rp[i + 1][j + 1] = racc;
    __syncthreads();

    // qr[a] = conv3x3(r, q_w)[a]  — iteration-invariant half of the VI update
    float rt[9];
    #pragma unroll
    for (int ky = 0; ky < 3; ++ky)
        #pragma unroll
        for (int kx = 0; kx < 3; ++kx)
            rt[ky * 3 + kx] = rp[i + ky][j + kx];

    float qr[LQ];
    #pragma unroll
    for (int a = 0; a < LQ; ++a) {
        float acc = 0.f;
        #pragma unroll
        for (int t = 0; t < 9; ++t) acc += rt[t] * qw[a * 9 + t];
        qr[a] = acc;
    }

    // hoist w into VGPRs (compile-time indices -> registers; wave-uniform but cheap)
    float wr[LQ * 9];
    #pragma unroll
    for (int k = 0; k < LQ * 9; ++k) wr[k] = w[k];

    // v0 = max_a qr[a]
    float v0 = qr[0];
    #pragma unroll
    for (int a = 1; a < LQ; ++a) v0 = fmaxf(v0, qr[a]);
    vp[0][i + 1][j + 1] = v0;
    __syncthreads();

    // K-1 = 19 value-iteration sweeps; double-buffered v => 1 barrier/iter
    int cur = 0;
    for (int it = 0; it < KITER - 1; ++it) {
        float vt[9];
        #pragma unroll
        for (int ky = 0; ky < 3; ++ky)
            #pragma unroll
            for (int kx = 0; kx < 3; ++kx)
                vt[ky * 3 + kx] = vp[cur][i + ky][j + kx];

        float m;
        #pragma unroll
        for (int a = 0; a < LQ; ++a) {
            float acc = qr[a];
            #pragma unroll
            for (int t = 0; t < 9; ++t) acc += vt[t] * wr[a * 9 + t];
            m = (a == 0) ? acc : fmaxf(m, acc);
        }
        vp[cur ^ 1][i + 1][j + 1] = m;
        __syncthreads();
        cur ^= 1;
    }

    // final conv + gather + fc only needed at pixel (s1, s2)
    const int s1 = min(max((int)floorf((S1[b] + 50.0f) * (1.0f / 6.25f) ), 0), IM - 1);
    const int s2 = min(max((int)floorf((S2[b] + 50.0f) * (1.0f / 6.25f) ), 0), IM - 1);
    if (i == s1 && j == s2) {
        float logit = 0.f;
        #pragma unroll
        for (int a = 0; a < LQ; ++a) logit += fcw[a] * qr[a];
        #pragma unroll
        for (int ky = 0; ky < 3; ++ky)
            #pragma unroll
            for (int kx = 0; kx < 3; ++kx)
                logit += vp[cur][i + ky][j + kx] * ws[19 + ky * 3 + kx];
        out[b]       = logit;       // logits
        out[B_N + b] = 1.0f;        // softmax over a length-1 axis is identically 1
    }
}

extern "C" void kernel_launch(void* const* d_in, const int* in_sizes, int n_in,
                              void* d_out, int out_size, void* d_ws, size_t ws_size,
                              hipStream_t stream) {
    const float* X    = (const float*)d_in[0];
    const float* S1   = (const float*)d_in[1];
    const float* S2   = (const float*)d_in[2];
    const float* h_w  = (const float*)d_in[3];
    const float* h_b  = (const float*)d_in[4];
    const float* r_w  = (const float*)d_in[5];
    const float* q_w  = (const float*)d_in[6];
    const float* w    = (const float*)d_in[7];
    const float* fc_w = (const float*)d_in[8];
    float*       out  = (float*)d_out;
    float*       ws   = (float*)d_ws;

    vin_precompute<<<1, 64, 0, stream>>>(h_w, h_b, r_w, w, fc_w, ws);
    vin_kernel<<<B_N, 256, 0, stream>>>(X, S1, S2, q_w, w, fc_w, ws, out);
}